// Round 7
// baseline (273.807 us; speedup 1.0000x reference)
//
#include <hip/hip_runtime.h>
#include <math.h>

typedef __attribute__((ext_vector_type(8))) short bf16x8;
typedef __attribute__((ext_vector_type(4))) float f32x4;

#define WFRAG (16 * 4 * 64 * 8)

// ---------------- helpers ----------------

__device__ inline int detect_is64(const int* __restrict__ ei) {
    int is64 = 1;
#pragma unroll
    for (int k = 1; k < 16; k += 2) is64 &= (ei[k] == 0);
    return is64;
}

__device__ inline void split1(float f, short& hi, short& lo) {
    unsigned u = __float_as_uint(f);
    hi = (short)(u >> 16);
    float fl = f - __uint_as_float(u & 0xffff0000u);
    lo = (short)(__float_as_uint(fl) >> 16);
}

__device__ inline void cvt8(const float4& a, const float4& b, bf16x8& hi, bf16x8& lo) {
    float f[8] = {a.x, a.y, a.z, a.w, b.x, b.y, b.z, b.w};
#pragma unroll
    for (int j = 0; j < 8; j++) {
        unsigned u = __float_as_uint(f[j]);
        hi[j] = (short)(u >> 16);
        float fl = f[j] - __uint_as_float(u & 0xffff0000u);
        lo[j] = (short)(__float_as_uint(fl) >> 16);
    }
}

// ---------------- prologue: prep_w (blocks 0..111) + cvt_x + degree count ----------------

__global__ __launch_bounds__(256) void prologue(const float* __restrict__ Wl,
                                                const float* __restrict__ Wr,
                                                short* __restrict__ Whi,
                                                short* __restrict__ Wlo,
                                                const float4* __restrict__ x4,
                                                short* __restrict__ cvH,
                                                short* __restrict__ cvL,
                                                const int* __restrict__ ei,
                                                int* __restrict__ deg,
                                                int N, int E) {
    __shared__ float Wt[128][17];
    int b = blockIdx.x, t = threadIdx.x;
    if (b < 112) {
        int l = b >> 4;
        int tile = b & 15;
        int c0 = tile * 16;
        const float* Wsrc = (c0 < 128) ? Wl + (size_t)l * 16384 : Wr + (size_t)l * 16384;
        int cbase = (c0 < 128) ? c0 : c0 - 128;
#pragma unroll
        for (int it = 0; it < 8; it++) {
            int idx = it * 256 + t;
            int k = idx >> 4, c = idx & 15;
            Wt[k][c] = Wsrc[(size_t)k * 128 + cbase + c];
        }
        __syncthreads();
        int kt = t >> 6, lane = t & 63, q = (lane >> 4), cl = lane & 15;
        bf16x8 hi, lo;
#pragma unroll
        for (int j = 0; j < 8; j++) {
            short h, lw;
            split1(Wt[kt * 32 + q * 8 + j][cl], h, lw);
            hi[j] = h; lo[j] = lw;
        }
        size_t off = ((((size_t)l * 16 + tile) * 4 + kt) * 64 + lane) * 8;
        *(bf16x8*)(Whi + off) = hi;
        *(bf16x8*)(Wlo + off) = lo;
        return;
    }
    int rb = b - 112;
    int RB = gridDim.x - 112;
    int n8 = N * 16;
    for (int id = rb * 256 + t; id < n8; id += RB * 256) {
        float4 a = x4[2 * id];
        float4 bb = x4[2 * id + 1];
        bf16x8 h, lw;
        cvt8(a, bb, h, lw);
        *(bf16x8*)(cvH + (size_t)id * 8) = h;
        *(bf16x8*)(cvL + (size_t)id * 8) = lw;
    }
    int is64 = detect_is64(ei);
    for (int e = rb * 256 + t; e < E; e += RB * 256) {
        long long pos = (long long)E + e;
        int d = ei[is64 ? 2 * pos : pos];
        if ((unsigned)d < (unsigned)N) atomicAdd(&deg[d], 1);
    }
}

// ---------------- scan (block 0) + layer-0 GEMM (blocks 1..) in ONE dispatch ----------------
// Both depend only on prologue; independent -> no internal sync needed.

__global__ __launch_bounds__(512, 1) void scan_gemm0(const int* __restrict__ deg,
                                                     int* __restrict__ offp,
                                                     int* __restrict__ cur, int N,
                                                     const short* __restrict__ xhi,
                                                     const short* __restrict__ xlo,
                                                     const short* __restrict__ WhiL,
                                                     const short* __restrict__ WloL,
                                                     const float* __restrict__ blv,
                                                     const float* __restrict__ brv,
                                                     float* __restrict__ xl,
                                                     float* __restrict__ xr,
                                                     int ntiles) {
    __shared__ int wsum[8];
    int t = threadIdx.x;
    if (blockIdx.x == 0) {
        // 512-thread inclusive scan of deg -> off/cur
        int per = (N + 511) >> 9;
        int b0 = t * per;
        int s = 0;
        for (int k = 0; k < per; k++) {
            int idx = b0 + k;
            if (idx < N) s += deg[idx];
        }
        int lane = t & 63, w = t >> 6;
        int v = s;
#pragma unroll
        for (int o = 1; o < 64; o <<= 1) {
            int u = __shfl_up(v, o, 64);
            if (lane >= o) v += u;
        }
        if (lane == 63) wsum[w] = v;
        __syncthreads();
        if (t == 0) {
            int r = 0;
#pragma unroll
            for (int j = 0; j < 8; j++) { int xx = wsum[j]; wsum[j] = r; r += xx; }
            offp[N] = r;
        }
        __syncthreads();
        int run = v - s + wsum[w];
        for (int k = 0; k < per; k++) {
            int idx = b0 + k;
            if (idx < N) {
                offp[idx] = run;
                cur[idx] = run;
                run += deg[idx];
            }
        }
        return;
    }

    // ---- layer-0 GEMM: A pre-split from prologue ----
    int w = t >> 6, lane = t & 63, q = lane >> 4, cl = lane & 15;

    bf16x8 Bh[2][4], Bl[2][4];
    float biasv[2];
    float* op[2];
    int colc[2];
#pragma unroll
    for (int nt = 0; nt < 2; nt++) {
        int tile = w * 2 + nt;
        int col = tile * 16 + cl;
        if (col < 128) { biasv[nt] = blv[col]; op[nt] = xl; colc[nt] = col; }
        else           { biasv[nt] = brv[col - 128]; op[nt] = xr; colc[nt] = col - 128; }
#pragma unroll
        for (int kt = 0; kt < 4; kt++) {
            size_t o = (((size_t)tile * 4 + kt) * 64 + lane) * 8;
            Bh[nt][kt] = *(const bf16x8*)(WhiL + o);
            Bl[nt][kt] = *(const bf16x8*)(WloL + o);
        }
    }

    for (int rt = blockIdx.x - 1; rt < ntiles; rt += gridDim.x - 1) {
        int row = rt * 16 + cl;
        if (row >= N) row = N - 1;
        const short* ph = xhi + (size_t)row * 128 + q * 8;
        const short* pl = xlo + (size_t)row * 128 + q * 8;
        bf16x8 AH[4], AL[4];
#pragma unroll
        for (int kt = 0; kt < 4; kt++) {
            AH[kt] = *(const bf16x8*)(ph + kt * 32);
            AL[kt] = *(const bf16x8*)(pl + kt * 32);
        }

        f32x4 acc0 = {0.f, 0.f, 0.f, 0.f}, acc1 = {0.f, 0.f, 0.f, 0.f};
#pragma unroll
        for (int kt = 0; kt < 4; kt++) {
            acc0 = __builtin_amdgcn_mfma_f32_16x16x32_bf16(AH[kt], Bh[0][kt], acc0, 0, 0, 0);
            acc1 = __builtin_amdgcn_mfma_f32_16x16x32_bf16(AH[kt], Bh[1][kt], acc1, 0, 0, 0);
            acc0 = __builtin_amdgcn_mfma_f32_16x16x32_bf16(AL[kt], Bh[0][kt], acc0, 0, 0, 0);
            acc1 = __builtin_amdgcn_mfma_f32_16x16x32_bf16(AL[kt], Bh[1][kt], acc1, 0, 0, 0);
            acc0 = __builtin_amdgcn_mfma_f32_16x16x32_bf16(AH[kt], Bl[0][kt], acc0, 0, 0, 0);
            acc1 = __builtin_amdgcn_mfma_f32_16x16x32_bf16(AH[kt], Bl[1][kt], acc1, 0, 0, 0);
        }

        // C/D layout: col = lane&15, row = quad*4 + reg  [m89-verified]
#pragma unroll
        for (int nt = 0; nt < 2; nt++) {
            f32x4 a = nt ? acc1 : acc0;
#pragma unroll
            for (int r = 0; r < 4; r++) {
                int orow = rt * 16 + q * 4 + r;
                if (orow < N) op[nt][(size_t)orow * 128 + colc[nt]] = a[r] + biasv[nt];
            }
        }
    }
}

__global__ void fill_kernel(const int* __restrict__ ei, int E, int N,
                            int* __restrict__ cur, int* __restrict__ esrc) {
    int e = blockIdx.x * blockDim.x + threadIdx.x;
    if (e >= E) return;
    int is64 = detect_is64(ei);
    long long spos = e, dpos = (long long)E + e;
    int s = ei[is64 ? 2 * spos : spos];
    int d = ei[is64 ? 2 * dpos : dpos];
    if ((unsigned)d >= (unsigned)N || (unsigned)s >= (unsigned)N) return;
    int p = atomicAdd(&cur[d], 1);
    esrc[p] = s;
}

// ---------------- agg core: one node per wave (round-2/6-verified body) ----------------

__device__ inline void agg_node(int i, int sub, int cl,
                                const float4* __restrict__ xl4, const float4* __restrict__ xr4,
                                const int* __restrict__ off, const int* __restrict__ esrc,
                                float4 atA, float4 atB, float4 bA, float4 bB,
                                float4& oA, float4& oB) {
    float4 xrA = xr4[(size_t)i * 32 + 2 * cl];
    float4 xrB = xr4[(size_t)i * 32 + 2 * cl + 1];
    int start = off[i];
    int total = off[i + 1] - start + 1;   // + self-loop at slot 0
    int groups = (total + 3) >> 2;

    int k0 = sub;
    int s0 = (k0 < total) ? ((k0 == 0) ? i : esrc[start + k0 - 1]) : i;
    int k1 = 4 + sub;
    int s1 = (k1 < total) ? esrc[start + k1 - 1] : i;
    float4 v0A = xl4[(size_t)s0 * 32 + 2 * cl];
    float4 v0B = xl4[(size_t)s0 * 32 + 2 * cl + 1];
    int k2 = 8 + sub;
    int s2 = (k2 < total) ? esrc[start + k2 - 1] : i;
    float4 v1A = xl4[(size_t)s1 * 32 + 2 * cl];
    float4 v1B = xl4[(size_t)s1 * 32 + 2 * cl + 1];

    float s = 0.f;
    float4 aA = make_float4(0.f, 0.f, 0.f, 0.f);
    float4 aB = make_float4(0.f, 0.f, 0.f, 0.f);

    for (int g = 0; g < groups; g++) {
        int k3 = 4 * (g + 3) + sub;
        int s3 = (k3 < total) ? esrc[start + k3 - 1] : i;
        float4 v2A = xl4[(size_t)s2 * 32 + 2 * cl];
        float4 v2B = xl4[(size_t)s2 * 32 + 2 * cl + 1];

        int kc = 4 * g + sub;
        int valid = kc < total;
        float z0 = v0A.x + xrA.x, z1 = v0A.y + xrA.y, z2 = v0A.z + xrA.z, z3 = v0A.w + xrA.w;
        float z4 = v0B.x + xrB.x, z5 = v0B.y + xrB.y, z6 = v0B.z + xrB.z, z7 = v0B.w + xrB.w;
        z0 = (z0 > 0.f) ? z0 : 0.2f * z0;
        z1 = (z1 > 0.f) ? z1 : 0.2f * z1;
        z2 = (z2 > 0.f) ? z2 : 0.2f * z2;
        z3 = (z3 > 0.f) ? z3 : 0.2f * z3;
        z4 = (z4 > 0.f) ? z4 : 0.2f * z4;
        z5 = (z5 > 0.f) ? z5 : 0.2f * z5;
        z6 = (z6 > 0.f) ? z6 : 0.2f * z6;
        z7 = (z7 > 0.f) ? z7 : 0.2f * z7;
        float p = z0 * atA.x + z1 * atA.y + z2 * atA.z + z3 * atA.w
                + z4 * atB.x + z5 * atB.y + z6 * atB.z + z7 * atB.w;
        p += __shfl_xor(p, 1, 64);
        p = fminf(fmaxf(p, -80.f), 80.f);
        float wgt = valid ? __expf(p) : 0.f;
        s += wgt;
        aA.x += wgt * v0A.x; aA.y += wgt * v0A.y; aA.z += wgt * v0A.z; aA.w += wgt * v0A.w;
        aB.x += wgt * v0B.x; aB.y += wgt * v0B.y; aB.z += wgt * v0B.z; aB.w += wgt * v0B.w;

        v0A = v1A; v0B = v1B;
        v1A = v2A; v1B = v2B;
        s2 = s3;
    }

#pragma unroll
    for (int o = 16; o <= 32; o <<= 1) {
        s += __shfl_xor(s, o, 64);
        aA.x += __shfl_xor(aA.x, o, 64); aA.y += __shfl_xor(aA.y, o, 64);
        aA.z += __shfl_xor(aA.z, o, 64); aA.w += __shfl_xor(aA.w, o, 64);
        aB.x += __shfl_xor(aB.x, o, 64); aB.y += __shfl_xor(aB.y, o, 64);
        aB.z += __shfl_xor(aB.z, o, 64); aB.w += __shfl_xor(aB.w, o, 64);
    }
    float inv = 1.f / (s + 1e-16f);
    oA.x = aA.x * inv + bA.x; oA.y = aA.y * inv + bA.y;
    oA.z = aA.z * inv + bA.z; oA.w = aA.w * inv + bA.w;
    oB.x = aB.x * inv + bB.x; oB.y = aB.y * inv + bB.y;
    oB.z = aB.z * inv + bB.z; oB.w = aB.w * inv + bB.w;
}

// ---------------- fused agg(l) + gemm(l+1): one block = 32 rows, 8 waves ----------------
// agg: 8 waves x 4 nodes -> split-bf16 rows in LDS; gemm: 32x256 tile, B regs loaded
// ONCE per wave (halves B L2 traffic vs 16-row blocks).

__global__ __launch_bounds__(512, 1) void agg_gemm(const float4* __restrict__ xl4,
                                                   const float4* __restrict__ xr4,
                                                   const int* __restrict__ off,
                                                   const int* __restrict__ esrc,
                                                   const float4* __restrict__ att4,
                                                   const float4* __restrict__ bias4,
                                                   const short* __restrict__ WhiL,
                                                   const short* __restrict__ WloL,
                                                   const float* __restrict__ blv,
                                                   const float* __restrict__ brv,
                                                   float* __restrict__ xlo_out,
                                                   float* __restrict__ xro_out,
                                                   int N) {
    __shared__ __align__(16) short hiL[32 * 136];
    __shared__ __align__(16) short loL[32 * 136];
    int t = threadIdx.x;
    int w = t >> 6, lane = t & 63, sub = lane >> 4, cl = lane & 15, q = lane >> 4;
    int base = blockIdx.x * 32;

    float4 atA = att4[2 * cl];
    float4 atB = att4[2 * cl + 1];
    float4 bA = bias4[2 * cl], bB = bias4[2 * cl + 1];

    // ---- agg: 4 nodes per wave ----
    for (int j = 0; j < 4; j++) {
        int i = base + w * 4 + j;
        if (i < N) {
            float4 oA, oB;
            agg_node(i, sub, cl, xl4, xr4, off, esrc, atA, atB, bA, bB, oA, oB);
            if (sub == 0) {
                bf16x8 h, lw;
                cvt8(oA, oB, h, lw);
                int r = w * 4 + j;
                *(bf16x8*)&hiL[r * 136 + cl * 8] = h;
                *(bf16x8*)&loL[r * 136 + cl * 8] = lw;
            }
        }
    }
    __syncthreads();

    // ---- gemm: wave w owns col-tiles {2w, 2w+1}; B loaded once ----
    bf16x8 Bh[2][4], Bl[2][4];
    float biasv[2];
    float* op[2];
    int cc[2];
#pragma unroll
    for (int tt = 0; tt < 2; tt++) {
        int tile = w * 2 + tt;
        int col = tile * 16 + cl;
        if (col < 128) { biasv[tt] = blv[col]; op[tt] = xlo_out; cc[tt] = col; }
        else           { biasv[tt] = brv[col - 128]; op[tt] = xro_out; cc[tt] = col - 128; }
#pragma unroll
        for (int kt = 0; kt < 4; kt++) {
            size_t o = (((size_t)tile * 4 + kt) * 64 + lane) * 8;
            Bh[tt][kt] = *(const bf16x8*)(WhiL + o);
            Bl[tt][kt] = *(const bf16x8*)(WloL + o);
        }
    }

#pragma unroll
    for (int m = 0; m < 2; m++) {
        bf16x8 Ah[4], Al[4];
#pragma unroll
        for (int kt = 0; kt < 4; kt++) {
            Ah[kt] = *(const bf16x8*)&hiL[(m * 16 + cl) * 136 + kt * 32 + q * 8];
            Al[kt] = *(const bf16x8*)&loL[(m * 16 + cl) * 136 + kt * 32 + q * 8];
        }
#pragma unroll
        for (int tt = 0; tt < 2; tt++) {
            f32x4 acc = {0.f, 0.f, 0.f, 0.f};
#pragma unroll
            for (int kt = 0; kt < 4; kt++) {
                acc = __builtin_amdgcn_mfma_f32_16x16x32_bf16(Ah[kt], Bh[tt][kt], acc, 0, 0, 0);
                acc = __builtin_amdgcn_mfma_f32_16x16x32_bf16(Al[kt], Bh[tt][kt], acc, 0, 0, 0);
                acc = __builtin_amdgcn_mfma_f32_16x16x32_bf16(Ah[kt], Bl[tt][kt], acc, 0, 0, 0);
            }
#pragma unroll
            for (int r = 0; r < 4; r++) {
                int row = base + m * 16 + q * 4 + r;
                if (row < N) op[tt][(size_t)row * 128 + cc[tt]] = acc[r] + biasv[tt];
            }
        }
    }
}

// ---------------- layer-6 agg + head fused: no xout materialization ----------------

__global__ __launch_bounds__(256) void gat_agg_head(const float4* __restrict__ xl4,
                                                    const float4* __restrict__ xr4,
                                                    const int* __restrict__ off,
                                                    const int* __restrict__ esrc,
                                                    const float4* __restrict__ att4,
                                                    const float4* __restrict__ bias4,
                                                    const float4* __restrict__ wh4,
                                                    const float* __restrict__ bh,
                                                    const int* __restrict__ nch,
                                                    float* __restrict__ out,
                                                    int n_out, int N) {
    int lane = threadIdx.x & 63;
    int sub = lane >> 4;
    int cl = lane & 15;
    int i = blockIdx.x * 4 + (threadIdx.x >> 6);
    if (i >= N) return;
    float4 atA = att4[2 * cl];
    float4 atB = att4[2 * cl + 1];
    float4 bA = bias4[2 * cl], bB = bias4[2 * cl + 1];
    float4 oA, oB;
    agg_node(i, sub, cl, xl4, xr4, off, esrc, atA, atB, bA, bB, oA, oB);
    if (sub == 0) {
        int chunk = 2 + nch[0];
        int r = i % chunk;
        if (r < 2) {
            float4 wa = wh4[2 * cl], wb = wh4[2 * cl + 1];
            float p = oA.x * wa.x + oA.y * wa.y + oA.z * wa.z + oA.w * wa.w
                    + oB.x * wb.x + oB.y * wb.y + oB.z * wb.z + oB.w * wb.w;
#pragma unroll
            for (int o = 1; o <= 8; o <<= 1) p += __shfl_xor(p, o, 64);
            if (cl == 0) {
                int b = (i / chunk) * 2 + r;
                if (b < n_out) out[b] = p + bh[0];
            }
        }
    }
}

// ---------------- launch ----------------

extern "C" void kernel_launch(void* const* d_in, const int* in_sizes, int n_in,
                              void* d_out, int out_size, void* d_ws, size_t ws_size,
                              hipStream_t stream) {
    const float* x0 = (const float*)d_in[0];
    const int* ei = (const int*)d_in[1];
    const int* nchunks = (const int*)d_in[2];
    const float* Wl = (const float*)d_in[3];
    const float* bl = (const float*)d_in[4];
    const float* Wr = (const float*)d_in[5];
    const float* br = (const float*)d_in[6];
    const float* att = (const float*)d_in[7];
    const float* bias = (const float*)d_in[8];
    const float* wh = (const float*)d_in[9];
    const float* bh = (const float*)d_in[10];

    const int D = 128;
    int N = in_sizes[0] / D;   // 10000
    int E = in_sizes[1] / 2;   // 160000
    int ntiles = (N + 15) / 16;

    size_t fN = (size_t)N * D;
    float* xlA = (float*)d_ws;
    float* xrA = xlA + fN;
    float* xlB = xrA + fN;
    float* xrB = xlB + fN;
    short* cvH0 = (short*)(xrB + fN);
    short* cvL0 = cvH0 + fN;
    short* Whi = cvL0 + fN;
    short* Wlo = Whi + 7 * (size_t)WFRAG;
    int* deg = (int*)(Wlo + 7 * (size_t)WFRAG);
    int* off = deg + N;
    int* cur = off + N + 1;
    int* esrc = cur + N;

    hipMemsetAsync(deg, 0, (size_t)N * sizeof(int), stream);
    prologue<<<112 + 640, 256, 0, stream>>>(Wl, Wr, Whi, Wlo, (const float4*)x0,
                                            cvH0, cvL0, ei, deg, N, E);
    // scan (block 0) + layer-0 GEMM (blocks 1..256) in one dispatch
    scan_gemm0<<<257, 512, 0, stream>>>(deg, off, cur, N, cvH0, cvL0, Whi, Wlo,
                                        bl, br, xlA, xrA, ntiles);
    fill_kernel<<<(E + 255) / 256, 256, 0, stream>>>(ei, E, N, cur, esrc);

    // layers 0..5: fused agg(l) + gemm(l+1), 32 rows/block, ping-pong xl/xr pairs
    int ablocks = (N + 31) / 32;
    for (int l = 0; l < 6; l++) {
        const float* rxl = (l % 2 == 0) ? xlA : xlB;
        const float* rxr = (l % 2 == 0) ? xrA : xrB;
        float* wxl = (l % 2 == 0) ? xlB : xlA;
        float* wxr = (l % 2 == 0) ? xrB : xrA;
        agg_gemm<<<ablocks, 512, 0, stream>>>((const float4*)rxl, (const float4*)rxr, off, esrc,
                                              (const float4*)(att + (size_t)l * D),
                                              (const float4*)(bias + (size_t)l * D),
                                              Whi + (size_t)(l + 1) * WFRAG,
                                              Wlo + (size_t)(l + 1) * WFRAG,
                                              bl + (size_t)(l + 1) * D,
                                              br + (size_t)(l + 1) * D,
                                              wxl, wxr, N);
    }

    // layer 6: agg + head fused (after l=5 the projections live in xlA/xrA)
    gat_agg_head<<<(N + 3) / 4, 256, 0, stream>>>((const float4*)xlA, (const float4*)xrA,
                                                  off, esrc,
                                                  (const float4*)(att + 6 * (size_t)D),
                                                  (const float4*)(bias + 6 * (size_t)D),
                                                  (const float4*)wh, bh, nchunks,
                                                  (float*)d_out, out_size, N);
}

// Round 8
// 270.280 us; speedup vs baseline: 1.0130x; 1.0130x over previous
//
#include <hip/hip_runtime.h>
#include <math.h>

typedef __attribute__((ext_vector_type(8))) short bf16x8;
typedef __attribute__((ext_vector_type(4))) float f32x4;

#define WFRAG (16 * 4 * 64 * 8)

// ---------------- helpers ----------------

__device__ inline int detect_is64(const int* __restrict__ ei) {
    int is64 = 1;
#pragma unroll
    for (int k = 1; k < 16; k += 2) is64 &= (ei[k] == 0);
    return is64;
}

__device__ inline void split1(float f, short& hi, short& lo) {
    unsigned u = __float_as_uint(f);
    hi = (short)(u >> 16);
    float fl = f - __uint_as_float(u & 0xffff0000u);
    lo = (short)(__float_as_uint(fl) >> 16);
}

__device__ inline void cvt8(const float4& a, const float4& b, bf16x8& hi, bf16x8& lo) {
    float f[8] = {a.x, a.y, a.z, a.w, b.x, b.y, b.z, b.w};
#pragma unroll
    for (int j = 0; j < 8; j++) {
        unsigned u = __float_as_uint(f[j]);
        hi[j] = (short)(u >> 16);
        float fl = f[j] - __uint_as_float(u & 0xffff0000u);
        lo[j] = (short)(__float_as_uint(fl) >> 16);
    }
}

// ---------------- prologue: prep_w (blocks 0..111) + cvt_x + degree count ----------------

__global__ __launch_bounds__(256) void prologue(const float* __restrict__ Wl,
                                                const float* __restrict__ Wr,
                                                short* __restrict__ Whi,
                                                short* __restrict__ Wlo,
                                                const float4* __restrict__ x4,
                                                short* __restrict__ cvH,
                                                short* __restrict__ cvL,
                                                const int* __restrict__ ei,
                                                int* __restrict__ deg,
                                                int N, int E) {
    __shared__ float Wt[128][17];
    int b = blockIdx.x, t = threadIdx.x;
    if (b < 112) {
        int l = b >> 4;
        int tile = b & 15;
        int c0 = tile * 16;
        const float* Wsrc = (c0 < 128) ? Wl + (size_t)l * 16384 : Wr + (size_t)l * 16384;
        int cbase = (c0 < 128) ? c0 : c0 - 128;
#pragma unroll
        for (int it = 0; it < 8; it++) {
            int idx = it * 256 + t;
            int k = idx >> 4, c = idx & 15;
            Wt[k][c] = Wsrc[(size_t)k * 128 + cbase + c];
        }
        __syncthreads();
        int kt = t >> 6, lane = t & 63, q = (lane >> 4), cl = lane & 15;
        bf16x8 hi, lo;
#pragma unroll
        for (int j = 0; j < 8; j++) {
            short h, lw;
            split1(Wt[kt * 32 + q * 8 + j][cl], h, lw);
            hi[j] = h; lo[j] = lw;
        }
        size_t off = ((((size_t)l * 16 + tile) * 4 + kt) * 64 + lane) * 8;
        *(bf16x8*)(Whi + off) = hi;
        *(bf16x8*)(Wlo + off) = lo;
        return;
    }
    int rb = b - 112;
    int RB = gridDim.x - 112;
    int n8 = N * 16;
    for (int id = rb * 256 + t; id < n8; id += RB * 256) {
        float4 a = x4[2 * id];
        float4 bb = x4[2 * id + 1];
        bf16x8 h, lw;
        cvt8(a, bb, h, lw);
        *(bf16x8*)(cvH + (size_t)id * 8) = h;
        *(bf16x8*)(cvL + (size_t)id * 8) = lw;
    }
    int is64 = detect_is64(ei);
    for (int e = rb * 256 + t; e < E; e += RB * 256) {
        long long pos = (long long)E + e;
        int d = ei[is64 ? 2 * pos : pos];
        if ((unsigned)d < (unsigned)N) atomicAdd(&deg[d], 1);
    }
}

// ---------------- scan (block 0) + layer-0 GEMM (blocks 1..) in ONE dispatch ----------------

__global__ __launch_bounds__(512, 1) void scan_gemm0(const int* __restrict__ deg,
                                                     int* __restrict__ offp,
                                                     int* __restrict__ cur, int N,
                                                     const short* __restrict__ xhi,
                                                     const short* __restrict__ xlo,
                                                     const short* __restrict__ WhiL,
                                                     const short* __restrict__ WloL,
                                                     const float* __restrict__ blv,
                                                     const float* __restrict__ brv,
                                                     float* __restrict__ xl,
                                                     float* __restrict__ xr,
                                                     int ntiles) {
    __shared__ int wsum[8];
    int t = threadIdx.x;
    if (blockIdx.x == 0) {
        int per = (N + 511) >> 9;
        int b0 = t * per;
        int s = 0;
        for (int k = 0; k < per; k++) {
            int idx = b0 + k;
            if (idx < N) s += deg[idx];
        }
        int lane = t & 63, w = t >> 6;
        int v = s;
#pragma unroll
        for (int o = 1; o < 64; o <<= 1) {
            int u = __shfl_up(v, o, 64);
            if (lane >= o) v += u;
        }
        if (lane == 63) wsum[w] = v;
        __syncthreads();
        if (t == 0) {
            int r = 0;
#pragma unroll
            for (int j = 0; j < 8; j++) { int xx = wsum[j]; wsum[j] = r; r += xx; }
            offp[N] = r;
        }
        __syncthreads();
        int run = v - s + wsum[w];
        for (int k = 0; k < per; k++) {
            int idx = b0 + k;
            if (idx < N) {
                offp[idx] = run;
                cur[idx] = run;
                run += deg[idx];
            }
        }
        return;
    }

    int w = t >> 6, lane = t & 63, q = lane >> 4, cl = lane & 15;

    bf16x8 Bh[2][4], Bl[2][4];
    float biasv[2];
    float* op[2];
    int colc[2];
#pragma unroll
    for (int nt = 0; nt < 2; nt++) {
        int tile = w * 2 + nt;
        int col = tile * 16 + cl;
        if (col < 128) { biasv[nt] = blv[col]; op[nt] = xl; colc[nt] = col; }
        else           { biasv[nt] = brv[col - 128]; op[nt] = xr; colc[nt] = col - 128; }
#pragma unroll
        for (int kt = 0; kt < 4; kt++) {
            size_t o = (((size_t)tile * 4 + kt) * 64 + lane) * 8;
            Bh[nt][kt] = *(const bf16x8*)(WhiL + o);
            Bl[nt][kt] = *(const bf16x8*)(WloL + o);
        }
    }

    for (int rt = blockIdx.x - 1; rt < ntiles; rt += gridDim.x - 1) {
        int row = rt * 16 + cl;
        if (row >= N) row = N - 1;
        const short* ph = xhi + (size_t)row * 128 + q * 8;
        const short* pl = xlo + (size_t)row * 128 + q * 8;
        bf16x8 AH[4], AL[4];
#pragma unroll
        for (int kt = 0; kt < 4; kt++) {
            AH[kt] = *(const bf16x8*)(ph + kt * 32);
            AL[kt] = *(const bf16x8*)(pl + kt * 32);
        }

        f32x4 acc0 = {0.f, 0.f, 0.f, 0.f}, acc1 = {0.f, 0.f, 0.f, 0.f};
#pragma unroll
        for (int kt = 0; kt < 4; kt++) {
            acc0 = __builtin_amdgcn_mfma_f32_16x16x32_bf16(AH[kt], Bh[0][kt], acc0, 0, 0, 0);
            acc1 = __builtin_amdgcn_mfma_f32_16x16x32_bf16(AH[kt], Bh[1][kt], acc1, 0, 0, 0);
            acc0 = __builtin_amdgcn_mfma_f32_16x16x32_bf16(AL[kt], Bh[0][kt], acc0, 0, 0, 0);
            acc1 = __builtin_amdgcn_mfma_f32_16x16x32_bf16(AL[kt], Bh[1][kt], acc1, 0, 0, 0);
            acc0 = __builtin_amdgcn_mfma_f32_16x16x32_bf16(AH[kt], Bl[0][kt], acc0, 0, 0, 0);
            acc1 = __builtin_amdgcn_mfma_f32_16x16x32_bf16(AH[kt], Bl[1][kt], acc1, 0, 0, 0);
        }

        // C/D layout: col = lane&15, row = quad*4 + reg  [m89-verified]
#pragma unroll
        for (int nt = 0; nt < 2; nt++) {
            f32x4 a = nt ? acc1 : acc0;
#pragma unroll
            for (int r = 0; r < 4; r++) {
                int orow = rt * 16 + q * 4 + r;
                if (orow < N) op[nt][(size_t)orow * 128 + colc[nt]] = a[r] + biasv[nt];
            }
        }
    }
}

__global__ void fill_kernel(const int* __restrict__ ei, int E, int N,
                            int* __restrict__ cur, int* __restrict__ esrc) {
    int e = blockIdx.x * blockDim.x + threadIdx.x;
    if (e >= E) return;
    int is64 = detect_is64(ei);
    long long spos = e, dpos = (long long)E + e;
    int s = ei[is64 ? 2 * spos : spos];
    int d = ei[is64 ? 2 * dpos : dpos];
    if ((unsigned)d >= (unsigned)N || (unsigned)s >= (unsigned)N) return;
    int p = atomicAdd(&cur[d], 1);
    esrc[p] = s;
}

// ---------------- agg core v2: one node per HALF-WAVE ----------------
// 32 lanes = 4 edge-slots (s) x 8 head-lanes (f). Lane owns head f's 16 features.
// Per-head logit is lane-local (no shuffle in hot loop); 4 float4 gather per lane
// doubles in-flight bytes; all nodes of a block aggregate concurrently.

__device__ inline void agg_node_hw(int i, int s, int f,
                                   const float4* __restrict__ xl4,
                                   const float4* __restrict__ xr4,
                                   const int* __restrict__ off,
                                   const int* __restrict__ esrc,
                                   const float4* __restrict__ att4,
                                   const float4* __restrict__ bias4,
                                   float4 (&out)[4]) {
    float4 xr0 = xr4[(size_t)i * 32 + f * 4 + 0];
    float4 xr1 = xr4[(size_t)i * 32 + f * 4 + 1];
    float4 xr2 = xr4[(size_t)i * 32 + f * 4 + 2];
    float4 xr3 = xr4[(size_t)i * 32 + f * 4 + 3];
    float4 at0 = att4[f * 4 + 0];
    float4 at1 = att4[f * 4 + 1];
    float4 at2 = att4[f * 4 + 2];
    float4 at3 = att4[f * 4 + 3];

    int start = off[i];
    int total = off[i + 1] - start + 1;   // + self-loop at slot 0
    int groups = (total + 3) >> 2;

    int k0 = s;
    int s0 = (k0 < total) ? ((k0 == 0) ? i : esrc[start + k0 - 1]) : i;
    const float4* p0 = xl4 + (size_t)s0 * 32 + f * 4;
    float4 a0 = p0[0], a1 = p0[1], a2 = p0[2], a3 = p0[3];
    int k1 = 4 + s;
    int s1 = (k1 < total) ? esrc[start + k1 - 1] : i;
    const float4* p1 = xl4 + (size_t)s1 * 32 + f * 4;
    float4 b0 = p1[0], b1 = p1[1], b2 = p1[2], b3 = p1[3];

    float denom = 0.f;
    float4 ac0 = make_float4(0.f, 0.f, 0.f, 0.f);
    float4 ac1 = make_float4(0.f, 0.f, 0.f, 0.f);
    float4 ac2 = make_float4(0.f, 0.f, 0.f, 0.f);
    float4 ac3 = make_float4(0.f, 0.f, 0.f, 0.f);

    for (int g = 0; g < groups; g++) {
        int k2 = (g + 2) * 4 + s;
        int s2 = (k2 < total) ? esrc[start + k2 - 1] : i;
        const float4* p2 = xl4 + (size_t)s2 * 32 + f * 4;
        float4 c0 = p2[0], c1 = p2[1], c2 = p2[2], c3 = p2[3];

        int valid = (g * 4 + s) < total;
#define LK(zz) ((zz) > 0.f ? (zz) : 0.2f * (zz))
        float p = 0.f, z;
        z = LK(a0.x + xr0.x); p += z * at0.x;
        z = LK(a0.y + xr0.y); p += z * at0.y;
        z = LK(a0.z + xr0.z); p += z * at0.z;
        z = LK(a0.w + xr0.w); p += z * at0.w;
        z = LK(a1.x + xr1.x); p += z * at1.x;
        z = LK(a1.y + xr1.y); p += z * at1.y;
        z = LK(a1.z + xr1.z); p += z * at1.z;
        z = LK(a1.w + xr1.w); p += z * at1.w;
        z = LK(a2.x + xr2.x); p += z * at2.x;
        z = LK(a2.y + xr2.y); p += z * at2.y;
        z = LK(a2.z + xr2.z); p += z * at2.z;
        z = LK(a2.w + xr2.w); p += z * at2.w;
        z = LK(a3.x + xr3.x); p += z * at3.x;
        z = LK(a3.y + xr3.y); p += z * at3.y;
        z = LK(a3.z + xr3.z); p += z * at3.z;
        z = LK(a3.w + xr3.w); p += z * at3.w;
#undef LK
        p = fminf(fmaxf(p, -80.f), 80.f);
        float wgt = valid ? __expf(p) : 0.f;
        denom += wgt;
        ac0.x += wgt * a0.x; ac0.y += wgt * a0.y; ac0.z += wgt * a0.z; ac0.w += wgt * a0.w;
        ac1.x += wgt * a1.x; ac1.y += wgt * a1.y; ac1.z += wgt * a1.z; ac1.w += wgt * a1.w;
        ac2.x += wgt * a2.x; ac2.y += wgt * a2.y; ac2.z += wgt * a2.z; ac2.w += wgt * a2.w;
        ac3.x += wgt * a3.x; ac3.y += wgt * a3.y; ac3.z += wgt * a3.z; ac3.w += wgt * a3.w;

        a0 = b0; a1 = b1; a2 = b2; a3 = b3;
        b0 = c0; b1 = c1; b2 = c2; b3 = c3;
    }

    // reduce over the 4 edge-slots (xor 8, 16 stays within the 32-lane half-wave)
#pragma unroll
    for (int o = 8; o <= 16; o <<= 1) {
        denom += __shfl_xor(denom, o, 64);
        ac0.x += __shfl_xor(ac0.x, o, 64); ac0.y += __shfl_xor(ac0.y, o, 64);
        ac0.z += __shfl_xor(ac0.z, o, 64); ac0.w += __shfl_xor(ac0.w, o, 64);
        ac1.x += __shfl_xor(ac1.x, o, 64); ac1.y += __shfl_xor(ac1.y, o, 64);
        ac1.z += __shfl_xor(ac1.z, o, 64); ac1.w += __shfl_xor(ac1.w, o, 64);
        ac2.x += __shfl_xor(ac2.x, o, 64); ac2.y += __shfl_xor(ac2.y, o, 64);
        ac2.z += __shfl_xor(ac2.z, o, 64); ac2.w += __shfl_xor(ac2.w, o, 64);
        ac3.x += __shfl_xor(ac3.x, o, 64); ac3.y += __shfl_xor(ac3.y, o, 64);
        ac3.z += __shfl_xor(ac3.z, o, 64); ac3.w += __shfl_xor(ac3.w, o, 64);
    }
    float inv = 1.f / (denom + 1e-16f);
    float4 bi0 = bias4[f * 4 + 0];
    float4 bi1 = bias4[f * 4 + 1];
    float4 bi2 = bias4[f * 4 + 2];
    float4 bi3 = bias4[f * 4 + 3];
    out[0].x = ac0.x * inv + bi0.x; out[0].y = ac0.y * inv + bi0.y;
    out[0].z = ac0.z * inv + bi0.z; out[0].w = ac0.w * inv + bi0.w;
    out[1].x = ac1.x * inv + bi1.x; out[1].y = ac1.y * inv + bi1.y;
    out[1].z = ac1.z * inv + bi1.z; out[1].w = ac1.w * inv + bi1.w;
    out[2].x = ac2.x * inv + bi2.x; out[2].y = ac2.y * inv + bi2.y;
    out[2].z = ac2.z * inv + bi2.z; out[2].w = ac2.w * inv + bi2.w;
    out[3].x = ac3.x * inv + bi3.x; out[3].y = ac3.y * inv + bi3.y;
    out[3].z = ac3.z * inv + bi3.z; out[3].w = ac3.w * inv + bi3.w;
}

// ---------------- fused agg(l) + gemm(l+1): 16 rows, 512 thr, 1 node/half-wave ----------------

__global__ __launch_bounds__(512, 2) void agg_gemm(const float4* __restrict__ xl4,
                                                   const float4* __restrict__ xr4,
                                                   const int* __restrict__ off,
                                                   const int* __restrict__ esrc,
                                                   const float4* __restrict__ att4,
                                                   const float4* __restrict__ bias4,
                                                   const short* __restrict__ WhiL,
                                                   const short* __restrict__ WloL,
                                                   const float* __restrict__ blv,
                                                   const float* __restrict__ brv,
                                                   float* __restrict__ xlo_out,
                                                   float* __restrict__ xro_out,
                                                   int N) {
    __shared__ __align__(16) short hiL[16 * 136];
    __shared__ __align__(16) short loL[16 * 136];
    int t = threadIdx.x;
    int hw = t >> 5;              // node slot 0..15
    int u = t & 31, s = u >> 3, f = u & 7;
    int base = blockIdx.x * 16;
    int i = base + hw;

    if (i < N) {
        float4 o[4];
        agg_node_hw(i, s, f, xl4, xr4, off, esrc, att4, bias4, o);
        if (s == 0) {
            bf16x8 h0, l0, h1, l1;
            cvt8(o[0], o[1], h0, l0);
            cvt8(o[2], o[3], h1, l1);
            *(bf16x8*)&hiL[hw * 136 + f * 16] = h0;
            *(bf16x8*)&hiL[hw * 136 + f * 16 + 8] = h1;
            *(bf16x8*)&loL[hw * 136 + f * 16] = l0;
            *(bf16x8*)&loL[hw * 136 + f * 16 + 8] = l1;
        }
    }
    __syncthreads();

    // ---- gemm: 8 waves x 2 col-tiles, B streamed (L2-hot) ----
    int w = t >> 6, lane = t & 63, q = lane >> 4, cl = lane & 15;
    bf16x8 Ah[4], Al[4];
#pragma unroll
    for (int kt = 0; kt < 4; kt++) {
        Ah[kt] = *(const bf16x8*)&hiL[cl * 136 + kt * 32 + q * 8];
        Al[kt] = *(const bf16x8*)&loL[cl * 136 + kt * 32 + q * 8];
    }

#pragma unroll
    for (int tt = 0; tt < 2; tt++) {
        int tile = w * 2 + tt;
        int col = tile * 16 + cl;
        f32x4 acc = {0.f, 0.f, 0.f, 0.f};
#pragma unroll
        for (int kt = 0; kt < 4; kt++) {
            size_t o = (((size_t)tile * 4 + kt) * 64 + lane) * 8;
            bf16x8 bh = *(const bf16x8*)(WhiL + o);
            bf16x8 bl2 = *(const bf16x8*)(WloL + o);
            acc = __builtin_amdgcn_mfma_f32_16x16x32_bf16(Ah[kt], bh, acc, 0, 0, 0);
            acc = __builtin_amdgcn_mfma_f32_16x16x32_bf16(Al[kt], bh, acc, 0, 0, 0);
            acc = __builtin_amdgcn_mfma_f32_16x16x32_bf16(Ah[kt], bl2, acc, 0, 0, 0);
        }
        float biasv;
        float* op;
        int cc;
        if (col < 128) { biasv = blv[col]; op = xlo_out; cc = col; }
        else           { biasv = brv[col - 128]; op = xro_out; cc = col - 128; }
#pragma unroll
        for (int r = 0; r < 4; r++) {
            int row = base + q * 4 + r;
            if (row < N) op[(size_t)row * 128 + cc] = acc[r] + biasv;
        }
    }
}

// ---------------- layer-6 agg + head fused (1 node per half-wave) ----------------

__global__ __launch_bounds__(256, 4) void gat_agg_head(const float4* __restrict__ xl4,
                                                       const float4* __restrict__ xr4,
                                                       const int* __restrict__ off,
                                                       const int* __restrict__ esrc,
                                                       const float4* __restrict__ att4,
                                                       const float4* __restrict__ bias4,
                                                       const float4* __restrict__ wh4,
                                                       const float* __restrict__ bh,
                                                       const int* __restrict__ nch,
                                                       float* __restrict__ out,
                                                       int n_out, int N) {
    int t = threadIdx.x;
    int hw = t >> 5;
    int u = t & 31, s = u >> 3, f = u & 7;
    int i = blockIdx.x * 8 + hw;
    if (i >= N) return;

    float4 o[4];
    agg_node_hw(i, s, f, xl4, xr4, off, esrc, att4, bias4, o);

    if (s == 0) {
        int chunk = 2 + nch[0];
        int r = i % chunk;
        if (r < 2) {
            float4 w0 = wh4[f * 4 + 0], w1 = wh4[f * 4 + 1];
            float4 w2 = wh4[f * 4 + 2], w3 = wh4[f * 4 + 3];
            float p = o[0].x * w0.x + o[0].y * w0.y + o[0].z * w0.z + o[0].w * w0.w
                    + o[1].x * w1.x + o[1].y * w1.y + o[1].z * w1.z + o[1].w * w1.w
                    + o[2].x * w2.x + o[2].y * w2.y + o[2].z * w2.z + o[2].w * w2.w
                    + o[3].x * w3.x + o[3].y * w3.y + o[3].z * w3.z + o[3].w * w3.w;
            // reduce over the 8 head-lanes (xor 1,2,4 stays within them)
            p += __shfl_xor(p, 1, 64);
            p += __shfl_xor(p, 2, 64);
            p += __shfl_xor(p, 4, 64);
            if (f == 0) {
                int b = (i / chunk) * 2 + r;
                if (b < n_out) out[b] = p + bh[0];
            }
        }
    }
}

// ---------------- launch ----------------

extern "C" void kernel_launch(void* const* d_in, const int* in_sizes, int n_in,
                              void* d_out, int out_size, void* d_ws, size_t ws_size,
                              hipStream_t stream) {
    const float* x0 = (const float*)d_in[0];
    const int* ei = (const int*)d_in[1];
    const int* nchunks = (const int*)d_in[2];
    const float* Wl = (const float*)d_in[3];
    const float* bl = (const float*)d_in[4];
    const float* Wr = (const float*)d_in[5];
    const float* br = (const float*)d_in[6];
    const float* att = (const float*)d_in[7];
    const float* bias = (const float*)d_in[8];
    const float* wh = (const float*)d_in[9];
    const float* bh = (const float*)d_in[10];

    const int D = 128;
    int N = in_sizes[0] / D;   // 10000
    int E = in_sizes[1] / 2;   // 160000
    int ntiles = (N + 15) / 16;

    size_t fN = (size_t)N * D;
    float* xlA = (float*)d_ws;
    float* xrA = xlA + fN;
    float* xlB = xrA + fN;
    float* xrB = xlB + fN;
    short* cvH0 = (short*)(xrB + fN);
    short* cvL0 = cvH0 + fN;
    short* Whi = cvL0 + fN;
    short* Wlo = Whi + 7 * (size_t)WFRAG;
    int* deg = (int*)(Wlo + 7 * (size_t)WFRAG);
    int* off = deg + N;
    int* cur = off + N + 1;
    int* esrc = cur + N;

    hipMemsetAsync(deg, 0, (size_t)N * sizeof(int), stream);
    prologue<<<112 + 640, 256, 0, stream>>>(Wl, Wr, Whi, Wlo, (const float4*)x0,
                                            cvH0, cvL0, ei, deg, N, E);
    scan_gemm0<<<257, 512, 0, stream>>>(deg, off, cur, N, cvH0, cvL0, Whi, Wlo,
                                        bl, br, xlA, xrA, ntiles);
    fill_kernel<<<(E + 255) / 256, 256, 0, stream>>>(ei, E, N, cur, esrc);

    // layers 0..5: fused agg(l) + gemm(l+1), 16 rows/block, 1 node per half-wave
    for (int l = 0; l < 6; l++) {
        const float* rxl = (l % 2 == 0) ? xlA : xlB;
        const float* rxr = (l % 2 == 0) ? xrA : xrB;
        float* wxl = (l % 2 == 0) ? xlB : xlA;
        float* wxr = (l % 2 == 0) ? xrB : xrA;
        agg_gemm<<<ntiles, 512, 0, stream>>>((const float4*)rxl, (const float4*)rxr, off, esrc,
                                             (const float4*)(att + (size_t)l * D),
                                             (const float4*)(bias + (size_t)l * D),
                                             Whi + (size_t)(l + 1) * WFRAG,
                                             Wlo + (size_t)(l + 1) * WFRAG,
                                             bl + (size_t)(l + 1) * D,
                                             br + (size_t)(l + 1) * D,
                                             wxl, wxr, N);
    }

    // layer 6: agg + head fused (after l=5 the projections live in xlA/xrA)
    gat_agg_head<<<(N + 7) / 8, 256, 0, stream>>>((const float4*)xlA, (const float4*)xrA,
                                                  off, esrc,
                                                  (const float4*)(att + 6 * (size_t)D),
                                                  (const float4*)(bias + 6 * (size_t)D),
                                                  (const float4*)wh, bh, nchunks,
                                                  (float*)d_out, out_size, N);
}